// Round 5
// baseline (524.636 us; speedup 1.0000x reference)
//
#include <hip/hip_runtime.h>

#define B_ 16
#define NTOK 785
#define C_ 768
#define HH 12
#define DH 64
#define BHN (B_*HH)       // 192
#define KVLEN 589
#define KVPAD 640
#define MROWS (B_*NTOK)   // 12560
#define HID 3072

typedef __bf16  bf16x8  __attribute__((ext_vector_type(8)));
typedef short   short4v __attribute__((ext_vector_type(4)));
typedef float   f32x4   __attribute__((ext_vector_type(4)));
typedef int     int4v   __attribute__((ext_vector_type(4)));
typedef unsigned short u16;

__device__ __forceinline__ u16 f2b(float f) {
  unsigned u = __builtin_bit_cast(unsigned, f);
  u = u + 0x7FFFu + ((u >> 16) & 1u);
  return (u16)(u >> 16);
}

#define AS1C(p) ((const __attribute__((address_space(1))) void*)(p))
#define AS3(p)  ((__attribute__((address_space(3))) void*)(p))
// 16B-granule XOR swizzle for [row][64] bf16 LDS tiles (element offset, g in 0..7)
#define SWZ(row, g) ((row)*64 + ((((g) ^ ((row)&7))) << 3))

// ---------------- workspace layout (bytes) ----------------
#define OFF_H   ((size_t)0)                    // 12560*768*2  = 19292160 (h / h2 bf16)
#define OFF_KF  ((size_t)19292160)             // kb bf16 (region 38584320) | g part1
#define OFF_QB  (OFF_KF + (size_t)38584320)    // 19292160 (q bf16)         | g part2
#define OFF_VB  (OFF_QB + (size_t)19292160)    // 19292160 (v bf16)         | g part3
#define OFF_KP  (OFF_VB + (size_t)19292160)    // 192*640*64*2 = 15728640 (packed k)
#define OFF_VP  (OFF_KP + (size_t)15728640)    // 15728640 (packed v, TRANSPOSED)
#define OFF_OB  (OFF_VP + (size_t)15728640)    // 19292160 (attn out bf16)
#define OFF_WQ  (OFF_OB + (size_t)19292160)    // 3538944
#define OFF_WP  (OFF_WQ + (size_t)3538944)     // 1179648
#define OFF_W1  (OFF_WP + (size_t)1179648)     // 4718592
#define OFF_W2  (OFF_W1 + (size_t)4718592)     // 4718592
#define OFF_SC  (OFF_W2 + (size_t)4718592)     // 602112
#define OFF_IX  (OFF_SC + (size_t)602112)      // 451584
#define OFF_G   OFF_KF                         // 77168640 == KF+QB+VB exactly

// ---------------- transpose + cast fp32 W[K][N] -> bf16 Wt[N][K] ----------------
__global__ __launch_bounds__(256)
void transpose_cast(const float* __restrict__ w, u16* __restrict__ wt, int K, int N) {
  __shared__ float T[64][65];
  const int k0 = blockIdx.x * 64, n0 = blockIdx.y * 64;
  const int tid = threadIdx.x;
  const int cc = tid & 63, rr = tid >> 6;
#pragma unroll
  for (int i = 0; i < 16; ++i) {
    int r = rr + i * 4;
    T[r][cc] = w[(size_t)(k0 + r) * N + n0 + cc];
  }
  __syncthreads();
#pragma unroll
  for (int i = 0; i < 16; ++i) {
    int r = rr + i * 4;
    wt[(size_t)(n0 + r) * K + k0 + cc] = f2b(T[cc][r]);
  }
}

// ---------------- layernorm: fp32 in -> bf16 out (row = 768) ----------------
__global__ __launch_bounds__(256)
void ln_kernel(const float* __restrict__ x, const float* __restrict__ g,
               const float* __restrict__ b, u16* __restrict__ out) {
  const int row = blockIdx.x;
  const int tid = threadIdx.x;
  const float* xr = x + (size_t)row * C_;
  float v0 = xr[tid], v1 = xr[tid + 256], v2 = xr[tid + 512];
  float sum = v0 + v1 + v2;
  float sq  = v0 * v0 + v1 * v1 + v2 * v2;
#pragma unroll
  for (int o = 32; o > 0; o >>= 1) { sum += __shfl_xor(sum, o); sq += __shfl_xor(sq, o); }
  __shared__ float rs[4], rq[4];
  int w = tid >> 6;
  if ((tid & 63) == 0) { rs[w] = sum; rq[w] = sq; }
  __syncthreads();
  sum = rs[0] + rs[1] + rs[2] + rs[3];
  sq  = rq[0] + rq[1] + rq[2] + rq[3];
  float mean = sum * (1.0f / C_);
  float var  = sq * (1.0f / C_) - mean * mean;
  float rstd = rsqrtf(var + 1e-5f);
  u16* orow = out + (size_t)row * C_;
  orow[tid]       = f2b((v0 - mean) * rstd * g[tid]       + b[tid]);
  orow[tid + 256] = f2b((v1 - mean) * rstd * g[tid + 256] + b[tid + 256]);
  orow[tid + 512] = f2b((v2 - mean) * rstd * g[tid + 512] + b[tid + 512]);
}

// ================= GEMM 256x256, 8 waves, phase-split, counted vmcnt =================
// T2 swizzle + T3/T4 counted prefetch + T5 setprio.  Raw s_barrier (no vmcnt(0) drain).
// Pipeline: tile t+1's 8 loads issued at iter-t top into the buffer freed by iter t-1
// (deterministically safe: issue follows iter-(t-1)'s final barrier). vmcnt(8) waits
// only the oldest 8 -> every tile has a full-iteration landing window.
// EPI 0: qkv scatter + fused k-norm scores.  EPI 2: gelu->bf16 (fc1).
template<int EPI>
__global__ __launch_bounds__(512, 2)
void gemm256(const u16* __restrict__ A, const u16* __restrict__ Bt,
             int M, int N, int K,
             const float* __restrict__ bias,
             u16* __restrict__ outb,
             u16* __restrict__ qb, u16* __restrict__ kb, u16* __restrict__ vb,
             float* __restrict__ sc) {
  __shared__ u16 As[2][256 * 64];   // 32KB each buf
  __shared__ u16 Bs[2][256 * 64];   // total 128KB
  const int tid = threadIdx.x;
  const int lane = tid & 63;
  const int wid = tid >> 6;
  const int wr = wid >> 2, wc = wid & 3;     // 2M x 4N waves; wave tile 128x64
  const int l15 = lane & 15;
  const int hi = lane >> 4;

  // m204 bijective XCD chunk swizzle
  const int CN = N >> 8;
  const int nwg = gridDim.x * gridDim.y;
  const int orig = blockIdx.x + blockIdx.y * gridDim.x;
  const int q = nwg >> 3, r8 = nwg & 7;
  const int xcd = orig & 7, pos = orig >> 3;
  const int wgid = (xcd < r8 ? xcd * (q + 1) : r8 * (q + 1) + (xcd - r8) * q) + pos;
  const int m0 = (wgid / CN) * 256;
  const int n0 = (wgid - (wgid / CN) * CN) * 256;

  // staging: round rr covers rows rr*64 + (tid>>3), 16B seg (tid&7); dest linear.
  const int srow = tid >> 3;
  const int sseg = tid & 7;
  const u16* aptr[4]; const u16* bptr[4]; int fl16[4];
#pragma unroll
  for (int i = 0; i < 4; ++i) {
    int row = i * 64 + srow;
    int gseg = sseg ^ (row & 7);            // pre-swizzled global source (rule 21)
    int gra = m0 + row; if (gra >= M) gra = M - 1;
    aptr[i] = A  + (size_t)gra * K        + gseg * 8;
    bptr[i] = Bt + (size_t)(n0 + row) * K + gseg * 8;
    fl16[i] = (i * 512 + tid) * 8;
  }

#define STAGE256(buf, kt)                                                        \
  {                                                                              \
    _Pragma("unroll")                                                            \
    for (int i = 0; i < 4; ++i) {                                                \
      __builtin_amdgcn_global_load_lds(AS1C(aptr[i] + (kt)),                     \
                                       AS3(&As[buf][fl16[i]]), 16, 0, 0);        \
      __builtin_amdgcn_global_load_lds(AS1C(bptr[i] + (kt)),                     \
                                       AS3(&Bs[buf][fl16[i]]), 16, 0, 0);        \
    }                                                                            \
  }

  f32x4 acc[8][4] = {};
  const int NT = K >> 6;

  STAGE256(0, 0);
  STAGE256(1, 64);

  for (int t = 0; t < NT; ++t) {
    const int cur = t & 1;
    if (t >= 1 && t + 1 < NT) STAGE256(cur ^ 1, (t + 1) * 64);
    if (t + 1 < NT) asm volatile("s_waitcnt vmcnt(8)" ::: "memory");
    else            asm volatile("s_waitcnt vmcnt(0)" ::: "memory");
    __builtin_amdgcn_s_barrier();

    bf16x8 b[4];
#define PHASE256(mh, kk, LOADB)                                                  \
    {                                                                            \
      if (LOADB) {                                                               \
        _Pragma("unroll")                                                        \
        for (int ni = 0; ni < 4; ++ni)                                           \
          b[ni] = *reinterpret_cast<const bf16x8*>(                              \
              &Bs[cur][SWZ(wc * 64 + ni * 16 + l15, (kk) * 4 + hi)]);            \
      }                                                                          \
      bf16x8 a[4];                                                               \
      _Pragma("unroll")                                                          \
      for (int mi = 0; mi < 4; ++mi)                                             \
        a[mi] = *reinterpret_cast<const bf16x8*>(                                \
            &As[cur][SWZ(wr * 128 + (mh) * 64 + mi * 16 + l15, (kk) * 4 + hi)]); \
      __builtin_amdgcn_s_setprio(1);                                             \
      _Pragma("unroll")                                                          \
      for (int mi = 0; mi < 4; ++mi)                                             \
        _Pragma("unroll")                                                        \
        for (int ni = 0; ni < 4; ++ni)                                           \
          acc[(mh) * 4 + mi][ni] = __builtin_amdgcn_mfma_f32_16x16x32_bf16(      \
              a[mi], b[ni], acc[(mh) * 4 + mi][ni], 0, 0, 0);                    \
      __builtin_amdgcn_s_setprio(0);                                             \
      __builtin_amdgcn_s_barrier();                                              \
    }
    PHASE256(0, 0, 1)
    PHASE256(1, 0, 0)
    PHASE256(0, 1, 1)
    PHASE256(1, 1, 0)
#undef PHASE256
  }
#undef STAGE256

#pragma unroll
  for (int am = 0; am < 8; ++am) {
#pragma unroll
    for (int ni = 0; ni < 4; ++ni) {
#pragma unroll
      for (int j = 0; j < 4; ++j) {
        int r = m0 + wr * 128 + am * 16 + hi * 4 + j;
        int c = n0 + wc * 64 + ni * 16 + l15;
        if (r < M) {
          float v = acc[am][ni][j];
          if (EPI == 0) {
            int sec = (c >= 1536) ? 2 : (c >= 768 ? 1 : 0);
            int cm = c - sec * 768;
            int hh = cm >> 6, d = cm & 63;
            int bb = r / NTOK; int nn = r - bb * NTOK;
            size_t addr = (((size_t)(bb * HH + hh)) * NTOK + nn) * DH + d;
            if (sec == 0)      qb[addr] = f2b(v);
            else if (sec == 1) kb[addr] = f2b(v);
            else               vb[addr] = f2b(v);
          } else {
            float tt = v + bias[c];
            outb[(size_t)r * N + c] = f2b(0.5f * tt * (1.0f + erff(tt * 0.70710678118654752f)));
          }
        }
      }
    }
  }

  if (EPI == 0) {
    int csec = n0 + wc * 64;
    if (csec >= 768 && csec < 1536) {
      int hh = (csec - 768) >> 6;
#pragma unroll
      for (int am = 0; am < 8; ++am) {
#pragma unroll
        for (int j = 0; j < 4; ++j) {
          float ss = 0.0f;
#pragma unroll
          for (int ni = 0; ni < 4; ++ni) { float v = acc[am][ni][j]; ss += v * v; }
          ss += __shfl_xor(ss, 1); ss += __shfl_xor(ss, 2);
          ss += __shfl_xor(ss, 4); ss += __shfl_xor(ss, 8);
          int r = m0 + wr * 128 + am * 16 + hi * 4 + j;
          if (l15 == 0 && r < M) {
            int bb = r / NTOK, nn = r - bb * NTOK;
            if (nn >= 1)
              sc[(size_t)(bb * HH + hh) * 784 + nn - 1] = sqrtf(ss) * (1.0f / 64.0f);
          }
        }
      }
    }
  }
}

// ---------------- GEMM 128x128: m97 single-buffer 2-barrier loop + XCD swizzle ----------------
// EPI 1: outf = acc + bias + addsrc (proj + residual)
// EPI 3: outf = acc + bias + addsrc (fc2 + residual, in-place on d_out)
template<int EPI>
__global__ __launch_bounds__(256, 2)
void gemm128(const u16* __restrict__ A, const u16* __restrict__ Bt,
             int M, int N, int K,
             const float* __restrict__ bias, const float* __restrict__ addsrc,
             float* __restrict__ outf) {
  __shared__ u16 As[128 * 64];
  __shared__ u16 Bs[128 * 64];
  const int tid = threadIdx.x;
  const int lane = tid & 63;
  const int w = tid >> 6;
  const int wm = w >> 1, wn = w & 1;
  const int l15 = lane & 15;
  const int hi = lane >> 4;

  const int CN = (N + 127) >> 7;
  const int nwg = gridDim.x * gridDim.y;
  const int orig = blockIdx.x + blockIdx.y * gridDim.x;
  const int q = nwg >> 3, r8 = nwg & 7;
  const int xcd = orig & 7, pos = orig >> 3;
  const int wgid = (xcd < r8 ? xcd * (q + 1) : r8 * (q + 1) + (xcd - r8) * q) + pos;
  const int m0 = (wgid / CN) * 128;
  const int n0 = (wgid - (wgid / CN) * CN) * 128;

  const int srow = tid >> 3;
  const int sseg = tid & 7;

  f32x4 acc[4][4] = {};

  for (int kt = 0; kt < K; kt += 64) {
    __syncthreads();
#pragma unroll
    for (int i = 0; i < 4; ++i) {
      int row = i * 32 + srow;
      int gseg = sseg ^ (row & 7);
      int gr = m0 + row; if (gr >= M) gr = M - 1;
      int flat = i * 256 + tid;
      __builtin_amdgcn_global_load_lds(AS1C(A  + (size_t)gr * K         + kt + gseg * 8),
                                       AS3(&As[flat * 8]), 16, 0, 0);
      __builtin_amdgcn_global_load_lds(AS1C(Bt + (size_t)(n0 + row) * K + kt + gseg * 8),
                                       AS3(&Bs[flat * 8]), 16, 0, 0);
    }
    __syncthreads();
#pragma unroll
    for (int kk = 0; kk < 2; ++kk) {
      bf16x8 a[4], b[4];
#pragma unroll
      for (int mi = 0; mi < 4; ++mi)
        a[mi] = *reinterpret_cast<const bf16x8*>(&As[SWZ(wm * 64 + mi * 16 + l15, kk * 4 + hi)]);
#pragma unroll
      for (int ni = 0; ni < 4; ++ni)
        b[ni] = *reinterpret_cast<const bf16x8*>(&Bs[SWZ(wn * 64 + ni * 16 + l15, kk * 4 + hi)]);
#pragma unroll
      for (int mi = 0; mi < 4; ++mi)
#pragma unroll
        for (int ni = 0; ni < 4; ++ni)
          acc[mi][ni] = __builtin_amdgcn_mfma_f32_16x16x32_bf16(a[mi], b[ni], acc[mi][ni], 0, 0, 0);
    }
  }

#pragma unroll
  for (int mi = 0; mi < 4; ++mi) {
#pragma unroll
    for (int ni = 0; ni < 4; ++ni) {
#pragma unroll
      for (int j = 0; j < 4; ++j) {
        int r = m0 + wm * 64 + mi * 16 + hi * 4 + j;
        int c = n0 + wn * 64 + ni * 16 + l15;
        if (r < M) {
          size_t o = (size_t)r * N + c;
          outf[o] = acc[mi][ni][j] + bias[c] + addsrc[o];
        }
      }
    }
  }
}

// ---------------- per-(b,h) top-588 selection, indices sorted ascending ----------------
__global__ __launch_bounds__(512)
void topk_kernel(const float* __restrict__ scores, int* __restrict__ idxb) {
  const int bh = blockIdx.x;
  const int tid = threadIdx.x;
  __shared__ float ss[1024];
  __shared__ int   sid[1024];
  __shared__ int   sid2[1024];
  for (int i = tid; i < 1024; i += 512) {
    ss[i]  = (i < 784) ? scores[bh * 784 + i] : -__builtin_inff();
    sid[i] = i;
  }
  for (int k = 2; k <= 1024; k <<= 1) {
    for (int j = k >> 1; j > 0; j >>= 1) {
      __syncthreads();
      for (int i = tid; i < 1024; i += 512) {
        int ixj = i ^ j;
        if (ixj > i) {
          float s1 = ss[i], s2 = ss[ixj];
          int   i1 = sid[i], i2 = sid[ixj];
          bool keep = (s1 > s2) || (s1 == s2 && i1 < i2);
          bool doSwap = ((i & k) == 0) ? !keep : keep;
          if (doSwap) { ss[i] = s2; ss[ixj] = s1; sid[i] = i2; sid[ixj] = i1; }
        }
      }
    }
  }
  __syncthreads();
  for (int i = tid; i < 1024; i += 512)
    sid2[i] = (i < 588) ? sid[i] : 0x7FFFFFFF;
  for (int k = 2; k <= 1024; k <<= 1) {
    for (int j = k >> 1; j > 0; j >>= 1) {
      __syncthreads();
      for (int i = tid; i < 1024; i += 512) {
        int ixj = i ^ j;
        if (ixj > i) {
          int a = sid2[i], b2 = sid2[ixj];
          bool keep = (a < b2);
          bool doSwap = ((i & k) == 0) ? !keep : keep;
          if (doSwap) { sid2[i] = b2; sid2[ixj] = a; }
        }
      }
    }
  }
  __syncthreads();
  for (int i = tid; i < 588; i += 512) idxb[bh * 588 + i] = sid2[i];
}

// ---------------- gather: kp row-major; vpT TRANSPOSED [bh][64 d][640 kv] ----------------
__global__ __launch_bounds__(256)
void gather_kernel(const u16* __restrict__ kb, const u16* __restrict__ vb,
                   const int* __restrict__ idxb, u16* __restrict__ kp, u16* __restrict__ vpT) {
  __shared__ u16 T[64 * 64];
  const int bh = blockIdx.x, chunk = blockIdx.y, t = threadIdx.x;
  {
    int jl = t >> 2, d0 = (t & 3) * 16;
    int j = chunk * 64 + jl;
    int n = (j == 0) ? 0 : (j <= 588 ? idxb[bh * 588 + j - 1] + 1 : -1);
    int4v k0 = {}, k1 = {}, v0 = {}, v1 = {};
    if (n >= 0) {
      size_t src = ((size_t)bh * NTOK + n) * DH + d0;
      k0 = *reinterpret_cast<const int4v*>(&kb[src]);
      k1 = *reinterpret_cast<const int4v*>(&kb[src + 8]);
      v0 = *reinterpret_cast<const int4v*>(&vb[src]);
      v1 = *reinterpret_cast<const int4v*>(&vb[src + 8]);
    }
    size_t kdst = ((size_t)bh * KVPAD + j) * DH + d0;
    *reinterpret_cast<int4v*>(&kp[kdst])     = k0;
    *reinterpret_cast<int4v*>(&kp[kdst + 8]) = k1;
    *reinterpret_cast<int4v*>(&T[jl * 64 + d0])     = v0;
    *reinterpret_cast<int4v*>(&T[jl * 64 + d0 + 8]) = v1;
  }
  __syncthreads();
  {
    int d = t & 63, kvo = (t >> 6) * 16;
    alignas(16) u16 tmp[16];
#pragma unroll
    for (int i = 0; i < 16; ++i) tmp[i] = T[(kvo + i) * 64 + d];
    size_t dst = ((size_t)bh * 64 + d) * KVPAD + chunk * 64 + kvo;
    *reinterpret_cast<int4v*>(&vpT[dst])     = *reinterpret_cast<int4v*>(&tmp[0]);
    *reinterpret_cast<int4v*>(&vpT[dst + 8]) = *reinterpret_cast<int4v*>(&tmp[8]);
  }
}

// ---------------- flash attention, swizzled LDS (conflict-free) ----------------
__global__ __launch_bounds__(256)
void attn_kernel(const u16* __restrict__ qb, const u16* __restrict__ kp,
                 const u16* __restrict__ vpT, u16* __restrict__ ob) {
  __shared__ u16 Qs[64 * 64];
  __shared__ u16 Ks[64 * 64];
  __shared__ u16 VTs[64 * 64];
  const int tid = threadIdx.x;
  const int lane = tid & 63;
  const int w = tid >> 6;
  const int l15 = lane & 15;
  const int hi = lane >> 4;
  const int bh = blockIdx.x;
  const int n0 = blockIdx.y * 64;

#pragma unroll
  for (int i = 0; i < 2; ++i) {
    int flat = i * 256 + tid;
    int row = flat >> 3, g = flat & 7;
    int4v val = {};
    if (n0 + row < NTOK)
      val = *reinterpret_cast<const int4v*>(qb + ((size_t)bh * NTOK + n0 + row) * DH + g * 8);
    *reinterpret_cast<int4v*>(&Qs[SWZ(row, g)]) = val;
  }
  __syncthreads();
  bf16x8 q0 = *reinterpret_cast<const bf16x8*>(&Qs[SWZ(w * 16 + l15, hi)]);
  bf16x8 q1 = *reinterpret_cast<const bf16x8*>(&Qs[SWZ(w * 16 + l15, 4 + hi)]);

  float m_run = -__builtin_inff(), l_run = 0.0f;
  f32x4 oa[4] = {};

  for (int kvt = 0; kvt < 10; ++kvt) {
    int4v kr[2], vr[2];
#pragma unroll
    for (int i = 0; i < 2; ++i) {
      int flat = i * 256 + tid;
      int row = flat >> 3, g = flat & 7;
      kr[i] = *reinterpret_cast<const int4v*>(kp  + ((size_t)bh * KVPAD + kvt * 64 + row) * DH + g * 8);
      vr[i] = *reinterpret_cast<const int4v*>(vpT + ((size_t)bh * 64 + row) * KVPAD + kvt * 64 + g * 8);
    }
    __syncthreads();
#pragma unroll
    for (int i = 0; i < 2; ++i) {
      int flat = i * 256 + tid;
      int row = flat >> 3, g = flat & 7;
      *reinterpret_cast<int4v*>(&Ks[SWZ(row, g)])  = kr[i];
      *reinterpret_cast<int4v*>(&VTs[SWZ(row, g)]) = vr[i];
    }
    __syncthreads();

    f32x4 st[4];
#pragma unroll
    for (int ft = 0; ft < 4; ++ft) {
      bf16x8 a0 = *reinterpret_cast<const bf16x8*>(&Ks[SWZ(ft * 16 + l15, hi)]);
      bf16x8 a1 = *reinterpret_cast<const bf16x8*>(&Ks[SWZ(ft * 16 + l15, 4 + hi)]);
      f32x4 cfr = {};
      cfr = __builtin_amdgcn_mfma_f32_16x16x32_bf16(a0, q0, cfr, 0, 0, 0);
      cfr = __builtin_amdgcn_mfma_f32_16x16x32_bf16(a1, q1, cfr, 0, 0, 0);
      st[ft] = cfr;
    }
    float mx = -__builtin_inff();
#pragma unroll
    for (int ft = 0; ft < 4; ++ft) {
#pragma unroll
      for (int j = 0; j < 4; ++j) {
        int kv = kvt * 64 + ft * 16 + hi * 4 + j;
        float s = st[ft][j] * 0.125f;
        s = (kv < KVLEN) ? s : -__builtin_inff();
        st[ft][j] = s;
        mx = fmaxf(mx, s);
      }
    }
    mx = fmaxf(mx, __shfl_xor(mx, 16));
    mx = fmaxf(mx, __shfl_xor(mx, 32));
    float m_new = fmaxf(m_run, mx);
    float alpha = __expf(m_run - m_new);
    float psum = 0.0f;
    short4v pb[4];
#pragma unroll
    for (int ft = 0; ft < 4; ++ft) {
#pragma unroll
      for (int j = 0; j < 4; ++j) {
        float p = __expf(st[ft][j] - m_new);
        psum += p;
        pb[ft][j] = (short)f2b(p);
      }
    }
    psum += __shfl_xor(psum, 16);
    psum += __shfl_xor(psum, 32);
    l_run = l_run * alpha + psum;
    m_run = m_new;
#pragma unroll
    for (int df = 0; df < 4; ++df) {
      oa[df][0] *= alpha; oa[df][1] *= alpha; oa[df][2] *= alpha; oa[df][3] *= alpha;
    }
#pragma unroll
    for (int df = 0; df < 4; ++df) {
#pragma unroll
      for (int ft = 0; ft < 4; ++ft) {
        short4v va = *reinterpret_cast<const short4v*>(
            &VTs[SWZ(df * 16 + l15, ft * 2 + (hi >> 1)) + (hi & 1) * 4]);
        oa[df] = __builtin_amdgcn_mfma_f32_16x16x16bf16_1k(va, pb[ft], oa[df], 0, 0, 0);
      }
    }
  }
  int n = n0 + w * 16 + l15;
  if (n < NTOK) {
    float inv = 1.0f / l_run;
    int bb = bh / HH, hh = bh - bb * HH;
    size_t base = ((size_t)bb * NTOK + n) * C_ + hh * DH;
#pragma unroll
    for (int df = 0; df < 4; ++df) {
      short4v pv;
#pragma unroll
      for (int j = 0; j < 4; ++j) pv[j] = (short)f2b(oa[df][j] * inv);
      *reinterpret_cast<short4v*>(ob + base + df * 16 + hi * 4) = pv;
    }
  }
}

// ---------------- launcher ----------------
extern "C" void kernel_launch(void* const* d_in, const int* in_sizes, int n_in,
                              void* d_out, int out_size, void* d_ws, size_t ws_size,
                              hipStream_t stream) {
  const float* x     = (const float*)d_in[0];
  const float* ln1g  = (const float*)d_in[1];
  const float* ln1b  = (const float*)d_in[2];
  const float* wqkv  = (const float*)d_in[3];
  const float* wproj = (const float*)d_in[4];
  const float* bproj = (const float*)d_in[5];
  const float* ln2g  = (const float*)d_in[6];
  const float* ln2b  = (const float*)d_in[7];
  const float* wfc1  = (const float*)d_in[8];
  const float* bfc1  = (const float*)d_in[9];
  const float* wfc2  = (const float*)d_in[10];
  const float* bfc2  = (const float*)d_in[11];
  float* out = (float*)d_out;
  char* wsb = (char*)d_ws;

  u16*   h     = (u16*)(wsb + OFF_H);
  u16*   kb    = (u16*)(wsb + OFF_KF);
  u16*   qb    = (u16*)(wsb + OFF_QB);
  u16*   vb    = (u16*)(wsb + OFF_VB);
  u16*   kp    = (u16*)(wsb + OFF_KP);
  u16*   vpT   = (u16*)(wsb + OFF_VP);
  u16*   ob    = (u16*)(wsb + OFF_OB);
  u16*   wqT   = (u16*)(wsb + OFF_WQ);
  u16*   wpT   = (u16*)(wsb + OFF_WP);
  u16*   w1T   = (u16*)(wsb + OFF_W1);
  u16*   w2T   = (u16*)(wsb + OFF_W2);
  float* sc    = (float*)(wsb + OFF_SC);
  int*   idxb  = (int*)(wsb + OFF_IX);
  u16*   g     = (u16*)(wsb + OFF_G);

  transpose_cast<<<dim3(768 / 64, 2304 / 64), 256, 0, stream>>>(wqkv, wqT, 768, 2304);
  transpose_cast<<<dim3(768 / 64, 768 / 64),  256, 0, stream>>>(wproj, wpT, 768, 768);
  transpose_cast<<<dim3(768 / 64, 3072 / 64), 256, 0, stream>>>(wfc1, w1T, 768, 3072);
  transpose_cast<<<dim3(3072 / 64, 768 / 64), 256, 0, stream>>>(wfc2, w2T, 3072, 768);

  ln_kernel<<<MROWS, 256, 0, stream>>>(x, ln1g, ln1b, h);

  // QKV gemm + fused scores (256^2 8-wave counted-vmcnt schedule)
  gemm256<0><<<dim3(2304 / 256, 50), 512, 0, stream>>>(h, wqT, MROWS, 2304, 768,
      nullptr, nullptr, qb, kb, vb, sc);

  topk_kernel<<<BHN, 512, 0, stream>>>(sc, idxb);
  gather_kernel<<<dim3(BHN, KVPAD / 64), 256, 0, stream>>>(kb, vb, idxb, kp, vpT);

  attn_kernel<<<dim3(BHN, 13), 256, 0, stream>>>(qb, kp, vpT, ob);

  // proj + residual -> x1 (in d_out)
  gemm128<1><<<dim3(768 / 128, 99), 256, 0, stream>>>(ob, wpT, MROWS, 768, 768,
      bproj, x, out);

  // LN2
  ln_kernel<<<MROWS, 256, 0, stream>>>(out, ln2g, ln2b, h);

  // fc1 + gelu -> g (256^2 schedule)
  gemm256<2><<<dim3(3072 / 256, 50), 512, 0, stream>>>(h, w1T, MROWS, 3072, 768,
      bfc1, g, nullptr, nullptr, nullptr, nullptr);

  // fc2 + bias + residual (in-place on d_out)
  gemm128<3><<<dim3(768 / 128, 99), 256, 0, stream>>>(g, w2T, MROWS, 768, 3072,
      bfc2, out, out);
}

// Round 6
// 454.906 us; speedup vs baseline: 1.1533x; 1.1533x over previous
//
#include <hip/hip_runtime.h>

#define B_ 16
#define NTOK 785
#define C_ 768
#define HH 12
#define DH 64
#define BHN (B_*HH)       // 192
#define KVLEN 589
#define KVPAD 640
#define MROWS (B_*NTOK)   // 12560
#define HID 3072

typedef __bf16  bf16x8  __attribute__((ext_vector_type(8)));
typedef short   short4v __attribute__((ext_vector_type(4)));
typedef float   f32x4   __attribute__((ext_vector_type(4)));
typedef int     int4v   __attribute__((ext_vector_type(4)));
typedef unsigned short u16;

__device__ __forceinline__ u16 f2b(float f) {
  unsigned u = __builtin_bit_cast(unsigned, f);
  u = u + 0x7FFFu + ((u >> 16) & 1u);
  return (u16)(u >> 16);
}

#define AS1C(p) ((const __attribute__((address_space(1))) void*)(p))
#define AS3(p)  ((__attribute__((address_space(3))) void*)(p))
// 16B-granule XOR swizzle for [row][64] bf16 LDS tiles (element offset, g in 0..7)
#define SWZ(row, g) ((row)*64 + ((((g) ^ ((row)&7))) << 3))

// ---------------- workspace layout (bytes) ----------------
#define OFF_H   ((size_t)0)                    // 12560*768*2  = 19292160 (h / h2 bf16)
#define OFF_KF  ((size_t)19292160)             // kb bf16 (region 38584320) | g part1
#define OFF_QB  (OFF_KF + (size_t)38584320)    // 19292160 (q bf16)         | g part2
#define OFF_VB  (OFF_QB + (size_t)19292160)    // 19292160 (v bf16)         | g part3
#define OFF_KP  (OFF_VB + (size_t)19292160)    // 192*640*64*2 = 15728640 (packed k)
#define OFF_VP  (OFF_KP + (size_t)15728640)    // 15728640 (packed v, TRANSPOSED)
#define OFF_OB  (OFF_VP + (size_t)15728640)    // 19292160 (attn out bf16)
#define OFF_WQ  (OFF_OB + (size_t)19292160)    // 3538944
#define OFF_WP  (OFF_WQ + (size_t)3538944)     // 1179648
#define OFF_W1  (OFF_WP + (size_t)1179648)     // 4718592
#define OFF_W2  (OFF_W1 + (size_t)4718592)     // 4718592
#define OFF_SC  (OFF_W2 + (size_t)4718592)     // 602112
#define OFF_IX  (OFF_SC + (size_t)602112)      // 451584
#define OFF_G   OFF_KF                         // 77168640 == KF+QB+VB exactly

// ---------------- transpose + cast fp32 W[K][N] -> bf16 Wt[N][K] ----------------
__global__ __launch_bounds__(256)
void transpose_cast(const float* __restrict__ w, u16* __restrict__ wt, int K, int N) {
  __shared__ float T[64][65];
  const int k0 = blockIdx.x * 64, n0 = blockIdx.y * 64;
  const int tid = threadIdx.x;
  const int cc = tid & 63, rr = tid >> 6;
#pragma unroll
  for (int i = 0; i < 16; ++i) {
    int r = rr + i * 4;
    T[r][cc] = w[(size_t)(k0 + r) * N + n0 + cc];
  }
  __syncthreads();
#pragma unroll
  for (int i = 0; i < 16; ++i) {
    int r = rr + i * 4;
    wt[(size_t)(n0 + r) * K + k0 + cc] = f2b(T[cc][r]);
  }
}

// ---------------- layernorm: fp32 in -> bf16 out (row = 768) ----------------
__global__ __launch_bounds__(256)
void ln_kernel(const float* __restrict__ x, const float* __restrict__ g,
               const float* __restrict__ b, u16* __restrict__ out) {
  const int row = blockIdx.x;
  const int tid = threadIdx.x;
  const float* xr = x + (size_t)row * C_;
  float v0 = xr[tid], v1 = xr[tid + 256], v2 = xr[tid + 512];
  float sum = v0 + v1 + v2;
  float sq  = v0 * v0 + v1 * v1 + v2 * v2;
#pragma unroll
  for (int o = 32; o > 0; o >>= 1) { sum += __shfl_xor(sum, o); sq += __shfl_xor(sq, o); }
  __shared__ float rs[4], rq[4];
  int w = tid >> 6;
  if ((tid & 63) == 0) { rs[w] = sum; rq[w] = sq; }
  __syncthreads();
  sum = rs[0] + rs[1] + rs[2] + rs[3];
  sq  = rq[0] + rq[1] + rq[2] + rq[3];
  float mean = sum * (1.0f / C_);
  float var  = sq * (1.0f / C_) - mean * mean;
  float rstd = rsqrtf(var + 1e-5f);
  u16* orow = out + (size_t)row * C_;
  orow[tid]       = f2b((v0 - mean) * rstd * g[tid]       + b[tid]);
  orow[tid + 256] = f2b((v1 - mean) * rstd * g[tid + 256] + b[tid + 256]);
  orow[tid + 512] = f2b((v2 - mean) * rstd * g[tid + 512] + b[tid + 512]);
}

// ---------------- GEMM 128x128: m97 single-buffer 2-barrier loop + XCD swizzle ----------------
// (R3/R5 post-mortems: explicit dbuf and invented phase schedules both regress;
//  this 2-barrier structure at ~5 blocks/CU is the proven local optimum.)
// EPI 0: qkv scatter (qb,kb,vb bf16) + fused k-norm scores
// EPI 1: outf = acc + bias + addsrc   (proj + residual, fp32)
// EPI 2: outb = bf16(gelu(acc+bias))  (fc1)
// EPI 3: outf = acc + bias + addsrc   (fc2 + residual, fp32, in-place on d_out)
template<int EPI>
__global__ __launch_bounds__(256, 2)
void gemm128(const u16* __restrict__ A, const u16* __restrict__ Bt,
             int M, int N, int K,
             const float* __restrict__ bias, const float* __restrict__ addsrc,
             float* __restrict__ outf, u16* __restrict__ outb,
             u16* __restrict__ qb, u16* __restrict__ kb, u16* __restrict__ vb,
             float* __restrict__ sc) {
  __shared__ u16 As[128 * 64];
  __shared__ u16 Bs[128 * 64];
  const int tid = threadIdx.x;
  const int lane = tid & 63;
  const int w = tid >> 6;
  const int wm = w >> 1, wn = w & 1;
  const int l15 = lane & 15;
  const int hi = lane >> 4;

  // m204 bijective XCD chunk swizzle: same-A-panel tiles land on one XCD,
  // temporally adjacent -> panel served from local L2 (~200cyc) not HBM (~900cyc).
  const int CN = (N + 127) >> 7;
  const int nwg = gridDim.x * gridDim.y;
  const int orig = blockIdx.x + blockIdx.y * gridDim.x;
  const int q = nwg >> 3, r8 = nwg & 7;
  const int xcd = orig & 7, pos = orig >> 3;
  const int wgid = (xcd < r8 ? xcd * (q + 1) : r8 * (q + 1) + (xcd - r8) * q) + pos;
  const int m0 = (wgid / CN) * 128;
  const int n0 = (wgid - (wgid / CN) * CN) * 128;

  const int srow = tid >> 3;   // staging base row (0..31), load i covers row i*32+srow
  const int sseg = tid & 7;

  f32x4 acc[4][4] = {};

  for (int kt = 0; kt < K; kt += 64) {
    __syncthreads();
#pragma unroll
    for (int i = 0; i < 4; ++i) {
      int row = i * 32 + srow;
      int gseg = sseg ^ (row & 7);           // pre-swizzled global source (rule 21)
      int gr = m0 + row; if (gr >= M) gr = M - 1;
      int flat = i * 256 + tid;
      __builtin_amdgcn_global_load_lds(AS1C(A  + (size_t)gr * K         + kt + gseg * 8),
                                       AS3(&As[flat * 8]), 16, 0, 0);
      __builtin_amdgcn_global_load_lds(AS1C(Bt + (size_t)(n0 + row) * K + kt + gseg * 8),
                                       AS3(&Bs[flat * 8]), 16, 0, 0);
    }
    __syncthreads();
#pragma unroll
    for (int kk = 0; kk < 2; ++kk) {
      bf16x8 a[4], b[4];
#pragma unroll
      for (int mi = 0; mi < 4; ++mi)
        a[mi] = *reinterpret_cast<const bf16x8*>(&As[SWZ(wm * 64 + mi * 16 + l15, kk * 4 + hi)]);
#pragma unroll
      for (int ni = 0; ni < 4; ++ni)
        b[ni] = *reinterpret_cast<const bf16x8*>(&Bs[SWZ(wn * 64 + ni * 16 + l15, kk * 4 + hi)]);
#pragma unroll
      for (int mi = 0; mi < 4; ++mi)
#pragma unroll
        for (int ni = 0; ni < 4; ++ni)
          acc[mi][ni] = __builtin_amdgcn_mfma_f32_16x16x32_bf16(a[mi], b[ni], acc[mi][ni], 0, 0, 0);
    }
  }

#pragma unroll
  for (int mi = 0; mi < 4; ++mi) {
#pragma unroll
    for (int ni = 0; ni < 4; ++ni) {
#pragma unroll
      for (int j = 0; j < 4; ++j) {
        int r = m0 + wm * 64 + mi * 16 + hi * 4 + j;
        int c = n0 + wn * 64 + ni * 16 + l15;
        if (r < M) {
          float v = acc[mi][ni][j];
          if (EPI == 0) {
            int sec = (c >= 1536) ? 2 : (c >= 768 ? 1 : 0);
            int cm = c - sec * 768;
            int hh = cm >> 6, d = cm & 63;
            int bb = r / NTOK; int nn = r - bb * NTOK;
            size_t addr = (((size_t)(bb * HH + hh)) * NTOK + nn) * DH + d;
            if (sec == 0)      qb[addr] = f2b(v);
            else if (sec == 1) kb[addr] = f2b(v);
            else               vb[addr] = f2b(v);
          } else if (EPI == 1) {
            size_t o = (size_t)r * N + c;
            outf[o] = v + bias[c] + addsrc[o];
          } else if (EPI == 2) {
            float t = v + bias[c];
            outb[(size_t)r * N + c] = f2b(0.5f * t * (1.0f + erff(t * 0.70710678118654752f)));
          } else {
            size_t o = (size_t)r * N + c;
            outf[o] = v + bias[c] + addsrc[o];
          }
        }
      }
    }
  }

  if (EPI == 0) {
    // fused k-norm scores: this wave's 64-col block == one head's d range iff in K section
    int csec = n0 + wn * 64;
    if (csec >= 768 && csec < 1536) {
      int hh = (csec - 768) >> 6;
#pragma unroll
      for (int mi = 0; mi < 4; ++mi) {
#pragma unroll
        for (int j = 0; j < 4; ++j) {
          float ss = 0.0f;
#pragma unroll
          for (int ni = 0; ni < 4; ++ni) { float v = acc[mi][ni][j]; ss += v * v; }
          ss += __shfl_xor(ss, 1); ss += __shfl_xor(ss, 2);
          ss += __shfl_xor(ss, 4); ss += __shfl_xor(ss, 8);
          int r = m0 + wm * 64 + mi * 16 + hi * 4 + j;
          if (l15 == 0 && r < M) {
            int bb = r / NTOK, nn = r - bb * NTOK;
            if (nn >= 1)
              sc[(size_t)(bb * HH + hh) * 784 + nn - 1] = sqrtf(ss) * (1.0f / 64.0f);
          }
        }
      }
    }
  }
}

// ---------------- per-(b,h) top-588 selection, indices sorted ascending ----------------
__global__ __launch_bounds__(512)
void topk_kernel(const float* __restrict__ scores, int* __restrict__ idxb) {
  const int bh = blockIdx.x;
  const int tid = threadIdx.x;
  __shared__ float ss[1024];
  __shared__ int   sid[1024];
  __shared__ int   sid2[1024];
  for (int i = tid; i < 1024; i += 512) {
    ss[i]  = (i < 784) ? scores[bh * 784 + i] : -__builtin_inff();
    sid[i] = i;
  }
  for (int k = 2; k <= 1024; k <<= 1) {
    for (int j = k >> 1; j > 0; j >>= 1) {
      __syncthreads();
      for (int i = tid; i < 1024; i += 512) {
        int ixj = i ^ j;
        if (ixj > i) {
          float s1 = ss[i], s2 = ss[ixj];
          int   i1 = sid[i], i2 = sid[ixj];
          bool keep = (s1 > s2) || (s1 == s2 && i1 < i2);
          bool doSwap = ((i & k) == 0) ? !keep : keep;
          if (doSwap) { ss[i] = s2; ss[ixj] = s1; sid[i] = i2; sid[ixj] = i1; }
        }
      }
    }
  }
  __syncthreads();
  for (int i = tid; i < 1024; i += 512)
    sid2[i] = (i < 588) ? sid[i] : 0x7FFFFFFF;
  for (int k = 2; k <= 1024; k <<= 1) {
    for (int j = k >> 1; j > 0; j >>= 1) {
      __syncthreads();
      for (int i = tid; i < 1024; i += 512) {
        int ixj = i ^ j;
        if (ixj > i) {
          int a = sid2[i], b2 = sid2[ixj];
          bool keep = (a < b2);
          bool doSwap = ((i & k) == 0) ? !keep : keep;
          if (doSwap) { sid2[i] = b2; sid2[ixj] = a; }
        }
      }
    }
  }
  __syncthreads();
  for (int i = tid; i < 588; i += 512) idxb[bh * 588 + i] = sid2[i];
}

// ---------------- gather: kp row-major; vpT TRANSPOSED [bh][64 d][640 kv] ----------------
__global__ __launch_bounds__(256)
void gather_kernel(const u16* __restrict__ kb, const u16* __restrict__ vb,
                   const int* __restrict__ idxb, u16* __restrict__ kp, u16* __restrict__ vpT) {
  __shared__ u16 T[64 * 64];
  const int bh = blockIdx.x, chunk = blockIdx.y, t = threadIdx.x;
  {
    int jl = t >> 2, d0 = (t & 3) * 16;
    int j = chunk * 64 + jl;
    int n = (j == 0) ? 0 : (j <= 588 ? idxb[bh * 588 + j - 1] + 1 : -1);
    int4v k0 = {}, k1 = {}, v0 = {}, v1 = {};
    if (n >= 0) {
      size_t src = ((size_t)bh * NTOK + n) * DH + d0;
      k0 = *reinterpret_cast<const int4v*>(&kb[src]);
      k1 = *reinterpret_cast<const int4v*>(&kb[src + 8]);
      v0 = *reinterpret_cast<const int4v*>(&vb[src]);
      v1 = *reinterpret_cast<const int4v*>(&vb[src + 8]);
    }
    size_t kdst = ((size_t)bh * KVPAD + j) * DH + d0;
    *reinterpret_cast<int4v*>(&kp[kdst])     = k0;
    *reinterpret_cast<int4v*>(&kp[kdst + 8]) = k1;
    *reinterpret_cast<int4v*>(&T[jl * 64 + d0])     = v0;
    *reinterpret_cast<int4v*>(&T[jl * 64 + d0 + 8]) = v1;
  }
  __syncthreads();
  {
    int d = t & 63, kvo = (t >> 6) * 16;
    alignas(16) u16 tmp[16];
#pragma unroll
    for (int i = 0; i < 16; ++i) tmp[i] = T[(kvo + i) * 64 + d];
    size_t dst = ((size_t)bh * 64 + d) * KVPAD + chunk * 64 + kvo;
    *reinterpret_cast<int4v*>(&vpT[dst])     = *reinterpret_cast<int4v*>(&tmp[0]);
    *reinterpret_cast<int4v*>(&vpT[dst + 8]) = *reinterpret_cast<int4v*>(&tmp[8]);
  }
}

// ---------------- flash attention, swizzled LDS, bh-major XCD-chunked grid ----------------
// 1D grid of 192*13 blocks. m204 swizzle, bh-major: one XCD chunk = 312 wgids =
// 24 bh; their K/V footprint (24 x 160KB = 3.84MB) fits that XCD's 4MB L2, so the
// 13 Q-chunks of each bh re-read K/V from local L2 instead of L3/HBM.
__global__ __launch_bounds__(256)
void attn_kernel(const u16* __restrict__ qb, const u16* __restrict__ kp,
                 const u16* __restrict__ vpT, u16* __restrict__ ob) {
  __shared__ u16 Qs[64 * 64];
  __shared__ u16 Ks[64 * 64];
  __shared__ u16 VTs[64 * 64];
  const int tid = threadIdx.x;
  const int lane = tid & 63;
  const int w = tid >> 6;
  const int l15 = lane & 15;
  const int hi = lane >> 4;

  const int nwg = gridDim.x;               // 2496 = 8*312
  const int orig = blockIdx.x;
  const int q = nwg >> 3, r8 = nwg & 7;
  const int xcd = orig & 7, pos = orig >> 3;
  const int wgid = (xcd < r8 ? xcd * (q + 1) : r8 * (q + 1) + (xcd - r8) * q) + pos;
  const int bh = wgid / 13;
  const int n0 = (wgid - bh * 13) * 64;

#pragma unroll
  for (int i = 0; i < 2; ++i) {
    int flat = i * 256 + tid;
    int row = flat >> 3, g = flat & 7;
    int4v val = {};
    if (n0 + row < NTOK)
      val = *reinterpret_cast<const int4v*>(qb + ((size_t)bh * NTOK + n0 + row) * DH + g * 8);
    *reinterpret_cast<int4v*>(&Qs[SWZ(row, g)]) = val;
  }
  __syncthreads();
  bf16x8 q0 = *reinterpret_cast<const bf16x8*>(&Qs[SWZ(w * 16 + l15, hi)]);
  bf16x8 q1 = *reinterpret_cast<const bf16x8*>(&Qs[SWZ(w * 16 + l15, 4 + hi)]);

  float m_run = -__builtin_inff(), l_run = 0.0f;
  f32x4 oa[4] = {};

  for (int kvt = 0; kvt < 10; ++kvt) {
    int4v kr[2], vr[2];
#pragma unroll
    for (int i = 0; i < 2; ++i) {
      int flat = i * 256 + tid;
      int row = flat >> 3, g = flat & 7;
      kr[i] = *reinterpret_cast<const int4v*>(kp  + ((size_t)bh * KVPAD + kvt * 64 + row) * DH + g * 8);
      vr[i] = *reinterpret_cast<const int4v*>(vpT + ((size_t)bh * 64 + row) * KVPAD + kvt * 64 + g * 8);
    }
    __syncthreads();
#pragma unroll
    for (int i = 0; i < 2; ++i) {
      int flat = i * 256 + tid;
      int row = flat >> 3, g = flat & 7;
      *reinterpret_cast<int4v*>(&Ks[SWZ(row, g)])  = kr[i];
      *reinterpret_cast<int4v*>(&VTs[SWZ(row, g)]) = vr[i];
    }
    __syncthreads();

    f32x4 st[4];
#pragma unroll
    for (int ft = 0; ft < 4; ++ft) {
      bf16x8 a0 = *reinterpret_cast<const bf16x8*>(&Ks[SWZ(ft * 16 + l15, hi)]);
      bf16x8 a1 = *reinterpret_cast<const bf16x8*>(&Ks[SWZ(ft * 16 + l15, 4 + hi)]);
      f32x4 cfr = {};
      cfr = __builtin_amdgcn_mfma_f32_16x16x32_bf16(a0, q0, cfr, 0, 0, 0);
      cfr = __builtin_amdgcn_mfma_f32_16x16x32_bf16(a1, q1, cfr, 0, 0, 0);
      st[ft] = cfr;
    }
    float mx = -__builtin_inff();
#pragma unroll
    for (int ft = 0; ft < 4; ++ft) {
#pragma unroll
      for (int j = 0; j < 4; ++j) {
        int kv = kvt * 64 + ft * 16 + hi * 4 + j;
        float s = st[ft][j] * 0.125f;
        s = (kv < KVLEN) ? s : -__builtin_inff();
        st[ft][j] = s;
        mx = fmaxf(mx, s);
      }
    }
    mx = fmaxf(mx, __shfl_xor(mx, 16));
    mx = fmaxf(mx, __shfl_xor(mx, 32));
    float m_new = fmaxf(m_run, mx);
    float alpha = __expf(m_run - m_new);
    float psum = 0.0f;
    short4v pb[4];
#pragma unroll
    for (int ft = 0; ft < 4; ++ft) {
#pragma unroll
      for (int j = 0; j < 4; ++j) {
        float p = __expf(st[ft][j] - m_new);
        psum += p;
        pb[ft][j] = (short)f2b(p);
      }
    }
    psum += __shfl_xor(psum, 16);
    psum += __shfl_xor(psum, 32);
    l_run = l_run * alpha + psum;
    m_run = m_new;
#pragma unroll
    for (int df = 0; df < 4; ++df) {
      oa[df][0] *= alpha; oa[df][1] *= alpha; oa[df][2] *= alpha; oa[df][3] *= alpha;
    }
#pragma unroll
    for (int df = 0; df < 4; ++df) {
#pragma unroll
      for (int ft = 0; ft < 4; ++ft) {
        short4v va = *reinterpret_cast<const short4v*>(
            &VTs[SWZ(df * 16 + l15, ft * 2 + (hi >> 1)) + (hi & 1) * 4]);
        oa[df] = __builtin_amdgcn_mfma_f32_16x16x16bf16_1k(va, pb[ft], oa[df], 0, 0, 0);
      }
    }
  }
  int n = n0 + w * 16 + l15;
  if (n < NTOK) {
    float inv = 1.0f / l_run;
    int bb = bh / HH, hh = bh - bb * HH;
    size_t base = ((size_t)bb * NTOK + n) * C_ + hh * DH;
#pragma unroll
    for (int df = 0; df < 4; ++df) {
      short4v pv;
#pragma unroll
      for (int j = 0; j < 4; ++j) pv[j] = (short)f2b(oa[df][j] * inv);
      *reinterpret_cast<short4v*>(ob + base + df * 16 + hi * 4) = pv;
    }
  }
}

// ---------------- launcher ----------------
extern "C" void kernel_launch(void* const* d_in, const int* in_sizes, int n_in,
                              void* d_out, int out_size, void* d_ws, size_t ws_size,
                              hipStream_t stream) {
  const float* x     = (const float*)d_in[0];
  const float* ln1g  = (const float*)d_in[1];
  const float* ln1b  = (const float*)d_in[2];
  const float* wqkv  = (const float*)d_in[3];
  const float* wproj = (const float*)d_in[4];
  const float* bproj = (const float*)d_in[5];
  const float* ln2g  = (const float*)d_in[6];
  const float* ln2b  = (const float*)d_in[7];
  const float* wfc1  = (const float*)d_in[8];
  const float* bfc1  = (const float*)d_in[9];
  const float* wfc2  = (const float*)d_in[10];
  const float* bfc2  = (const float*)d_in[11];
  float* out = (float*)d_out;
  char* wsb = (char*)d_ws;

  u16*   h     = (u16*)(wsb + OFF_H);
  u16*   kb    = (u16*)(wsb + OFF_KF);
  u16*   qb    = (u16*)(wsb + OFF_QB);
  u16*   vb    = (u16*)(wsb + OFF_VB);
  u16*   kp    = (u16*)(wsb + OFF_KP);
  u16*   vpT   = (u16*)(wsb + OFF_VP);
  u16*   ob    = (u16*)(wsb + OFF_OB);
  u16*   wqT   = (u16*)(wsb + OFF_WQ);
  u16*   wpT   = (u16*)(wsb + OFF_WP);
  u16*   w1T   = (u16*)(wsb + OFF_W1);
  u16*   w2T   = (u16*)(wsb + OFF_W2);
  float* sc    = (float*)(wsb + OFF_SC);
  int*   idxb  = (int*)(wsb + OFF_IX);
  u16*   g     = (u16*)(wsb + OFF_G);

  transpose_cast<<<dim3(768 / 64, 2304 / 64), 256, 0, stream>>>(wqkv, wqT, 768, 2304);
  transpose_cast<<<dim3(768 / 64, 768 / 64),  256, 0, stream>>>(wproj, wpT, 768, 768);
  transpose_cast<<<dim3(768 / 64, 3072 / 64), 256, 0, stream>>>(wfc1, w1T, 768, 3072);
  transpose_cast<<<dim3(3072 / 64, 768 / 64), 256, 0, stream>>>(wfc2, w2T, 3072, 768);

  ln_kernel<<<MROWS, 256, 0, stream>>>(x, ln1g, ln1b, h);

  // QKV gemm + fused scores
  gemm128<0><<<dim3(2304 / 128, 99), 256, 0, stream>>>(h, wqT, MROWS, 2304, 768,
      nullptr, nullptr, nullptr, nullptr, qb, kb, vb, sc);

  topk_kernel<<<BHN, 512, 0, stream>>>(sc, idxb);
  gather_kernel<<<dim3(BHN, KVPAD / 64), 256, 0, stream>>>(kb, vb, idxb, kp, vpT);

  // attention: 1D bh-major grid with XCD chunk swizzle (K/V L2 locality)
  attn_kernel<<<BHN * 13, 256, 0, stream>>>(qb, kp, vpT, ob);

  // proj + residual -> x1 (in d_out)
  gemm128<1><<<dim3(768 / 128, 99), 256, 0, stream>>>(ob, wpT, MROWS, 768, 768,
      bproj, x, out, nullptr, nullptr, nullptr, nullptr, nullptr);

  // LN2
  ln_kernel<<<MROWS, 256, 0, stream>>>(out, ln2g, ln2b, h);

  // fc1 + gelu -> g
  gemm128<2><<<dim3(3072 / 128, 99), 256, 0, stream>>>(h, w1T, MROWS, 3072, 768,
      bfc1, nullptr, nullptr, g, nullptr, nullptr, nullptr, nullptr);

  // fc2 + bias + residual (in-place on d_out)
  gemm128<3><<<dim3(768 / 128, 99), 256, 0, stream>>>(g, w2T, MROWS, 768, 3072,
      bfc2, out, out, nullptr, nullptr, nullptr, nullptr, nullptr);
}